// Round 1
// baseline (449.256 us; speedup 1.0000x reference)
//
#include <hip/hip_runtime.h>
#include <cstdint>

static constexpr int B    = 16;
static constexpr int P    = 22536;
static constexpr int NOBJ = 32;
static constexpr int NCLS = 80;
static constexpr int BP   = B * P;

// stable log_sigmoid(x) = -softplus(-x)
__device__ __forceinline__ float logsig(float x) {
  return (x >= 0.f) ? -log1pf(expf(-x)) : (x - log1pf(expf(x)));
}

// ---------------------------------------------------------------- init
__global__ __launch_bounds__(256) void k_init(unsigned long long* objbest,
                                              int* npos, float* sums) {
  int i = blockIdx.x * 256 + threadIdx.x;
  if (i < B * NOBJ) objbest[i] = 0ull;
  if (i == 0) { *npos = 0; sums[0] = 0.f; sums[1] = 0.f; }
}

// ---------------------------------------------------------------- match
// Per prior: max/argmax IoU over 32 objects (first-occurrence tie-break).
// Per object: max/argmax IoU over priors via packed u64 atomicMax;
// packing (iou_bits<<32)|~prior gives first-occurrence (lowest prior) on ties.
__global__ __launch_bounds__(256) void k_match(
    const float4* __restrict__ boxes, const float4* __restrict__ priors,
    float* __restrict__ ovp, int* __restrict__ objp,
    unsigned long long* __restrict__ objbest) {
  const int b   = blockIdx.y;
  const int p   = blockIdx.x * 256 + threadIdx.x;
  const int tid = threadIdx.x;
  __shared__ float4 sbox[NOBJ];
  __shared__ float  sarea[NOBJ];
  __shared__ unsigned long long sbest[NOBJ];
  if (tid < NOBJ) {
    float4 bx = boxes[b * NOBJ + tid];
    sbox[tid]  = bx;
    sarea[tid] = (bx.z - bx.x) * (bx.w - bx.y);  // same op order as reference
    sbest[tid] = 0ull;
  }
  __syncthreads();
  if (p < P) {
    float4 pc = priors[p];
    float hx = pc.z * 0.5f, hy = pc.w * 0.5f;     // c/2. == c*0.5f exactly
    float px0 = pc.x - hx, py0 = pc.y - hy;
    float px1 = pc.x + hx, py1 = pc.y + hy;
    float parea = (px1 - px0) * (py1 - py0);      // area from xy, like reference
    float best = -1.f; int bobj = 0;
    for (int o = 0; o < NOBJ; ++o) {
      float4 bx = sbox[o];
      float lx = fmaxf(bx.x, px0), ly = fmaxf(bx.y, py0);
      float rx = fminf(bx.z, px1), ry = fminf(bx.w, py1);
      float w = fmaxf(rx - lx, 0.f), h = fmaxf(ry - ly, 0.f);
      float inter = w * h;
      float iou = inter / (sarea[o] + parea - inter);
      if (iou > best) { best = iou; bobj = o; }   // strict >: first max wins
      unsigned long long pk =
          ((unsigned long long)__float_as_uint(iou) << 32) |
          (unsigned long long)(unsigned)(~(unsigned)p);
      atomicMax(&sbest[o], pk);
    }
    ovp[b * P + p]  = best;
    objp[b * P + p] = bobj;
  }
  __syncthreads();
  if (tid < NOBJ) atomicMax(&objbest[b * NOBJ + tid], sbest[tid]);
}

// ---------------------------------------------------------------- force-set
// Sequential per image: last-writer-wins in object order (JAX/numpy scatter).
// filt = cumsum(valid)-1 quirk: forced prior gets the FILTERED object index.
__global__ void k_force(const unsigned long long* __restrict__ objbest,
                        float* __restrict__ ovp, int* __restrict__ objp) {
  int b = blockIdx.x * blockDim.x + threadIdx.x;
  if (b < B) {
    int cnt = 0;
    for (int j = 0; j < NOBJ; ++j) {
      unsigned long long pk = objbest[b * NOBJ + j];
      float iou = __uint_as_float((unsigned)(pk >> 32));
      if (iou > 0.f) {
        unsigned pr = ~(unsigned)(pk & 0xFFFFFFFFull);
        ovp[b * P + (int)pr]  = 1.0f;
        objp[b * P + (int)pr] = cnt;
        ++cnt;
      }
    }
  }
}

// ---------------------------------------------------------------- class + loc
__global__ __launch_bounds__(256) void k_classloc(
    const float* __restrict__ ovp, const int* __restrict__ objp,
    const int* __restrict__ labels, const float4* __restrict__ boxes,
    const float4* __restrict__ priors, const float4* __restrict__ plocs,
    int* __restrict__ tclass, int* __restrict__ npos, float* __restrict__ sums) {
  int i = blockIdx.x * 256 + threadIdx.x;
  int myPos = 0; float mySl1 = 0.f;
  if (i < BP) {
    int b = i / P;
    int p = i - b * P;
    float ov = ovp[i];
    int obj  = objp[i];
    int lab;
    if (ov < 0.4f)      lab = 0;    // fp32(0.5-0.1) == 0.4f
    else if (ov < 0.5f) lab = -1;
    else                lab = labels[b * NOBJ + obj];
    tclass[i] = lab;
    if (lab > 0) {
      myPos = 1;
      float4 bx = boxes[b * NOBJ + obj];          // quirky filtered index, like ref
      float cx = (bx.x + bx.z) * 0.5f;            // (b[:2]+b[2:])/2
      float cy = (bx.y + bx.w) * 0.5f;
      float cw = bx.z - bx.x;
      float ch = bx.w - bx.y;
      float4 pc = priors[p];
      float gx = (cx - pc.x) / (pc.z / 10.f);     // keep the /10. division
      float gy = (cy - pc.y) / (pc.w / 10.f);
      float gw = logf(cw / pc.z) * 5.f;
      float gh = logf(ch / pc.w) * 5.f;
      float4 pl = plocs[i];
      float d, a;
      d = pl.x - gx; a = fabsf(d); mySl1 += (a < 1.f) ? 0.5f * d * d : a - 0.5f;
      d = pl.y - gy; a = fabsf(d); mySl1 += (a < 1.f) ? 0.5f * d * d : a - 0.5f;
      d = pl.z - gw; a = fabsf(d); mySl1 += (a < 1.f) ? 0.5f * d * d : a - 0.5f;
      d = pl.w - gh; a = fabsf(d); mySl1 += (a < 1.f) ? 0.5f * d * d : a - 0.5f;
    }
  }
  // block reduce (4 waves)
  for (int o = 32; o > 0; o >>= 1) {
    mySl1 += __shfl_down(mySl1, o, 64);
    myPos += __shfl_down(myPos, o, 64);
  }
  __shared__ float sv[4];
  __shared__ int   sc[4];
  int lane = threadIdx.x & 63, wid = threadIdx.x >> 6;
  if (lane == 0) { sv[wid] = mySl1; sc[wid] = myPos; }
  __syncthreads();
  if (threadIdx.x == 0) {
    atomicAdd(&sums[0], sv[0] + sv[1] + sv[2] + sv[3]);
    atomicAdd(npos,     sc[0] + sc[1] + sc[2] + sc[3]);
  }
}

// ---------------------------------------------------------------- focal
__global__ __launch_bounds__(256) void k_focal(
    const float4* __restrict__ scores, const int* __restrict__ tclass,
    float* __restrict__ sums) {
  constexpr int Q = NCLS / 4;              // 20 float4 per prior
  constexpr int total4 = BP * Q;           // 7,211,520
  float acc = 0.f;
  for (int i = blockIdx.x * 256 + threadIdx.x; i < total4; i += gridDim.x * 256) {
    int prior = i / Q;
    int k4    = i - prior * Q;
    int t = tclass[prior];
    if (t < 0) continue;                   // ignore (-1): zero contribution
    float4 s = scores[i];
    int kbase = k4 * 4 + 1;                // 1-indexed class of s.x
    float xs[4] = {s.x, s.y, s.z, s.w};
    #pragma unroll
    for (int j = 0; j < 4; ++j) {
      float x  = xs[j];
      float pz = 1.f / (1.f + expf(-x));
      if (t == kbase + j) {
        float omp = 1.f - pz;
        acc -= 0.25f * omp * omp * logsig(x);
      } else {
        acc -= 0.75f * pz * pz * logsig(-x);
      }
    }
  }
  for (int o = 32; o > 0; o >>= 1) acc += __shfl_down(acc, o, 64);
  __shared__ float sv[4];
  int lane = threadIdx.x & 63, wid = threadIdx.x >> 6;
  if (lane == 0) sv[wid] = acc;
  __syncthreads();
  if (threadIdx.x == 0) atomicAdd(&sums[1], sv[0] + sv[1] + sv[2] + sv[3]);
}

// ---------------------------------------------------------------- final
__global__ void k_final(const int* __restrict__ npos,
                        const float* __restrict__ sums, float* __restrict__ out) {
  if (threadIdx.x == 0 && blockIdx.x == 0) {
    int n = *npos;
    float np = (float)(n > 1 ? n : 1);
    out[0] = sums[1] / np + sums[0] / (np * 4.f);
  }
}

// ---------------------------------------------------------------- launch
extern "C" void kernel_launch(void* const* d_in, const int* in_sizes, int n_in,
                              void* d_out, int out_size, void* d_ws, size_t ws_size,
                              hipStream_t stream) {
  const float* plocs   = (const float*)d_in[0];   // [B,P,4]
  const float* pscores = (const float*)d_in[1];   // [B,P,80]
  const float* boxes   = (const float*)d_in[2];   // [B,32,4]
  const int*   labels  = (const int*)d_in[3];     // [B,32]
  const float* priors  = (const float*)d_in[4];   // [P,4]
  float* out = (float*)d_out;

  char* w = (char*)d_ws;
  float* ovp  = (float*)(w);                       // BP f32
  int*   objp = (int*)(w + 4ull * BP);             // BP i32
  int*   tcls = (int*)(w + 8ull * BP);             // BP i32
  unsigned long long* objbest =
      (unsigned long long*)(w + 12ull * BP);       // B*NOBJ u64
  int*   npos = (int*)(w + 12ull * BP + 8ull * B * NOBJ);
  float* sums = (float*)(w + 12ull * BP + 8ull * B * NOBJ + 8);

  k_init<<<2, 256, 0, stream>>>(objbest, npos, sums);
  dim3 mg((P + 255) / 256, B);
  k_match<<<mg, 256, 0, stream>>>((const float4*)boxes, (const float4*)priors,
                                  ovp, objp, objbest);
  k_force<<<1, 64, 0, stream>>>(objbest, ovp, objp);
  k_classloc<<<(BP + 255) / 256, 256, 0, stream>>>(
      ovp, objp, labels, (const float4*)boxes, (const float4*)priors,
      (const float4*)plocs, tcls, npos, sums);
  k_focal<<<2048, 256, 0, stream>>>((const float4*)pscores, tcls, sums);
  k_final<<<1, 64, 0, stream>>>(npos, sums, out);
}

// Round 2
// 125.113 us; speedup vs baseline: 3.5908x; 3.5908x over previous
//
#include <hip/hip_runtime.h>
#include <cstdint>

static constexpr int B    = 16;
static constexpr int P    = 22536;
static constexpr int NOBJ = 32;
static constexpr int NCLS = 80;
static constexpr int BP   = B * P;

// ---------------------------------------------------------------- init
__global__ void k_init(int* npos, float* sums) {
  if (threadIdx.x == 0) { *npos = 0; sums[0] = 0.f; sums[1] = 0.f; }
}

// ---------------------------------------------------------------- match A: per-prior argmax over objects
__global__ __launch_bounds__(256) void k_match(
    const float4* __restrict__ boxes, const float4* __restrict__ priors,
    float* __restrict__ ovp, int* __restrict__ objp) {
  const int b   = blockIdx.y;
  const int p   = blockIdx.x * 256 + threadIdx.x;
  const int tid = threadIdx.x;
  __shared__ float4 sbox[NOBJ];
  __shared__ float  sarea[NOBJ];
  if (tid < NOBJ) {
    float4 bx = boxes[b * NOBJ + tid];
    sbox[tid]  = bx;
    sarea[tid] = (bx.z - bx.x) * (bx.w - bx.y);  // same op order as reference
  }
  __syncthreads();
  if (p < P) {
    float4 pc = priors[p];
    float hx = pc.z * 0.5f, hy = pc.w * 0.5f;     // c/2. == c*0.5f exactly
    float px0 = pc.x - hx, py0 = pc.y - hy;
    float px1 = pc.x + hx, py1 = pc.y + hy;
    float parea = (px1 - px0) * (py1 - py0);
    float best = -1.f; int bobj = 0;
    #pragma unroll 8
    for (int o = 0; o < NOBJ; ++o) {
      float4 bx = sbox[o];
      float lx = fmaxf(bx.x, px0), ly = fmaxf(bx.y, py0);
      float rx = fminf(bx.z, px1), ry = fminf(bx.w, py1);
      float w = fmaxf(rx - lx, 0.f), h = fmaxf(ry - ly, 0.f);
      float inter = w * h;
      float iou = inter / (sarea[o] + parea - inter);
      if (iou > best) { best = iou; bobj = o; }   // strict >: first max wins
    }
    ovp[b * P + p]  = best;
    objp[b * P + p] = bobj;
  }
}

// ---------------------------------------------------------------- match B: per-object argmax over priors
// One block per (image, object); no atomics. Packed (iou_bits<<32)|~prior:
// u64 max => max iou, ties prefer smallest prior (first-occurrence, like argmax).
__global__ __launch_bounds__(256) void k_objbest(
    const float4* __restrict__ boxes, const float4* __restrict__ priors,
    unsigned long long* __restrict__ objbest) {
  const int b = blockIdx.x >> 5;          // /NOBJ
  const int o = blockIdx.x & (NOBJ - 1);
  float4 bx = boxes[b * NOBJ + o];
  float barea = (bx.z - bx.x) * (bx.w - bx.y);
  unsigned long long best = 0ull;
  for (int p = threadIdx.x; p < P; p += 256) {
    float4 pc = priors[p];
    float hx = pc.z * 0.5f, hy = pc.w * 0.5f;
    float px0 = pc.x - hx, py0 = pc.y - hy;
    float px1 = pc.x + hx, py1 = pc.y + hy;
    float parea = (px1 - px0) * (py1 - py0);
    float lx = fmaxf(bx.x, px0), ly = fmaxf(bx.y, py0);
    float rx = fminf(bx.z, px1), ry = fminf(bx.w, py1);
    float w = fmaxf(rx - lx, 0.f), h = fmaxf(ry - ly, 0.f);
    float inter = w * h;
    float iou = inter / (barea + parea - inter);
    unsigned long long pk =
        ((unsigned long long)__float_as_uint(iou) << 32) |
        (unsigned long long)(unsigned)(~(unsigned)p);
    best = (pk > best) ? pk : best;
  }
  for (int off = 32; off > 0; off >>= 1) {
    unsigned long long other = __shfl_down(best, off, 64);
    best = (other > best) ? other : best;
  }
  __shared__ unsigned long long sb[4];
  int lane = threadIdx.x & 63, wid = threadIdx.x >> 6;
  if (lane == 0) sb[wid] = best;
  __syncthreads();
  if (threadIdx.x == 0) {
    unsigned long long r = sb[0];
    r = (sb[1] > r) ? sb[1] : r;
    r = (sb[2] > r) ? sb[2] : r;
    r = (sb[3] > r) ? sb[3] : r;
    objbest[blockIdx.x] = r;
  }
}

// ---------------------------------------------------------------- force-set
// Sequential per image: last-writer-wins in object order (JAX scatter semantics).
// filt = cumsum(valid)-1 quirk: forced prior gets the FILTERED object index.
__global__ void k_force(const unsigned long long* __restrict__ objbest,
                        float* __restrict__ ovp, int* __restrict__ objp) {
  int b = blockIdx.x * blockDim.x + threadIdx.x;
  if (b < B) {
    int cnt = 0;
    for (int j = 0; j < NOBJ; ++j) {
      unsigned long long pk = objbest[b * NOBJ + j];
      float iou = __uint_as_float((unsigned)(pk >> 32));
      if (iou > 0.f) {
        unsigned pr = ~(unsigned)(pk & 0xFFFFFFFFull);
        ovp[b * P + (int)pr]  = 1.0f;
        objp[b * P + (int)pr] = cnt;
        ++cnt;
      }
    }
  }
}

// ---------------------------------------------------------------- class + loc
__global__ __launch_bounds__(256) void k_classloc(
    const float* __restrict__ ovp, const int* __restrict__ objp,
    const int* __restrict__ labels, const float4* __restrict__ boxes,
    const float4* __restrict__ priors, const float4* __restrict__ plocs,
    int* __restrict__ tclass, int* __restrict__ npos, float* __restrict__ sums) {
  int i = blockIdx.x * 256 + threadIdx.x;
  int myPos = 0; float mySl1 = 0.f;
  if (i < BP) {
    int b = i / P;
    int p = i - b * P;
    float ov = ovp[i];
    int obj  = objp[i];
    int lab;
    if (ov < 0.4f)      lab = 0;    // fp32(0.5-0.1) == 0.4f
    else if (ov < 0.5f) lab = -1;
    else                lab = labels[b * NOBJ + obj];
    tclass[i] = lab;
    if (lab > 0) {
      myPos = 1;
      float4 bx = boxes[b * NOBJ + obj];          // quirky filtered index, like ref
      float cx = (bx.x + bx.z) * 0.5f;
      float cy = (bx.y + bx.w) * 0.5f;
      float cw = bx.z - bx.x;
      float ch = bx.w - bx.y;
      float4 pc = priors[p];
      float gx = (cx - pc.x) / (pc.z / 10.f);     // keep the /10. division
      float gy = (cy - pc.y) / (pc.w / 10.f);
      float gw = logf(cw / pc.z) * 5.f;
      float gh = logf(ch / pc.w) * 5.f;
      float4 pl = plocs[i];
      float d, a;
      d = pl.x - gx; a = fabsf(d); mySl1 += (a < 1.f) ? 0.5f * d * d : a - 0.5f;
      d = pl.y - gy; a = fabsf(d); mySl1 += (a < 1.f) ? 0.5f * d * d : a - 0.5f;
      d = pl.z - gw; a = fabsf(d); mySl1 += (a < 1.f) ? 0.5f * d * d : a - 0.5f;
      d = pl.w - gh; a = fabsf(d); mySl1 += (a < 1.f) ? 0.5f * d * d : a - 0.5f;
    }
  }
  for (int o = 32; o > 0; o >>= 1) {
    mySl1 += __shfl_down(mySl1, o, 64);
    myPos += __shfl_down(myPos, o, 64);
  }
  __shared__ float sv[4];
  __shared__ int   sc[4];
  int lane = threadIdx.x & 63, wid = threadIdx.x >> 6;
  if (lane == 0) { sv[wid] = mySl1; sc[wid] = myPos; }
  __syncthreads();
  if (threadIdx.x == 0) {
    atomicAdd(&sums[0], sv[0] + sv[1] + sv[2] + sv[3]);
    atomicAdd(npos,     sc[0] + sc[1] + sc[2] + sc[3]);
  }
}

// ---------------------------------------------------------------- focal
// One expf per element: e = exp(-x); p = 1/(1+e); 1-p = e*p;
// logsig(x) = -log(1+e); logsig(-x) = logsig(x) - x.
__global__ __launch_bounds__(256) void k_focal(
    const float4* __restrict__ scores, const int* __restrict__ tclass,
    float* __restrict__ sums) {
  constexpr int Q = NCLS / 4;              // 20 float4 per prior
  constexpr int total4 = BP * Q;           // 7,211,520
  float acc = 0.f;
  for (int i = blockIdx.x * 256 + threadIdx.x; i < total4; i += gridDim.x * 256) {
    int prior = i / Q;
    int k4    = i - prior * Q;
    int t = tclass[prior];
    if (t < 0) continue;                   // ignore (-1): zero contribution
    float4 s = scores[i];
    int kbase = k4 * 4 + 1;                // 1-indexed class of s.x
    float xs[4] = {s.x, s.y, s.z, s.w};
    #pragma unroll
    for (int j = 0; j < 4; ++j) {
      float x   = xs[j];
      float e   = __expf(-x);
      float r   = __builtin_amdgcn_rcpf(1.f + e);   // p = sigmoid(x)
      float lsp = -__logf(1.f + e);                 // log sigmoid(x)
      bool  pos = (t == kbase + j);
      float c   = pos ? 0.25f : 0.75f;
      float q   = pos ? e * r : r;                  // (1-p) : p
      float l   = pos ? lsp : lsp - x;              // logp : logn
      acc -= c * q * q * l;
    }
  }
  for (int o = 32; o > 0; o >>= 1) acc += __shfl_down(acc, o, 64);
  __shared__ float sv[4];
  int lane = threadIdx.x & 63, wid = threadIdx.x >> 6;
  if (lane == 0) sv[wid] = acc;
  __syncthreads();
  if (threadIdx.x == 0) atomicAdd(&sums[1], sv[0] + sv[1] + sv[2] + sv[3]);
}

// ---------------------------------------------------------------- final
__global__ void k_final(const int* __restrict__ npos,
                        const float* __restrict__ sums, float* __restrict__ out) {
  if (threadIdx.x == 0 && blockIdx.x == 0) {
    int n = *npos;
    float np = (float)(n >= 1 ? n : 1);
    out[0] = sums[1] / np + sums[0] / (np * 4.f);
  }
}

// ---------------------------------------------------------------- launch
extern "C" void kernel_launch(void* const* d_in, const int* in_sizes, int n_in,
                              void* d_out, int out_size, void* d_ws, size_t ws_size,
                              hipStream_t stream) {
  const float* plocs   = (const float*)d_in[0];   // [B,P,4]
  const float* pscores = (const float*)d_in[1];   // [B,P,80]
  const float* boxes   = (const float*)d_in[2];   // [B,32,4]
  const int*   labels  = (const int*)d_in[3];     // [B,32]
  const float* priors  = (const float*)d_in[4];   // [P,4]
  float* out = (float*)d_out;

  char* w = (char*)d_ws;
  float* ovp  = (float*)(w);                       // BP f32
  int*   objp = (int*)(w + 4ull * BP);             // BP i32
  int*   tcls = (int*)(w + 8ull * BP);             // BP i32
  unsigned long long* objbest =
      (unsigned long long*)(w + 12ull * BP);       // B*NOBJ u64
  int*   npos = (int*)(w + 12ull * BP + 8ull * B * NOBJ);
  float* sums = (float*)(w + 12ull * BP + 8ull * B * NOBJ + 8);

  k_init<<<1, 64, 0, stream>>>(npos, sums);
  dim3 mg((P + 255) / 256, B);
  k_match<<<mg, 256, 0, stream>>>((const float4*)boxes, (const float4*)priors,
                                  ovp, objp);
  k_objbest<<<B * NOBJ, 256, 0, stream>>>((const float4*)boxes,
                                          (const float4*)priors, objbest);
  k_force<<<1, 64, 0, stream>>>(objbest, ovp, objp);
  k_classloc<<<(BP + 255) / 256, 256, 0, stream>>>(
      ovp, objp, labels, (const float4*)boxes, (const float4*)priors,
      (const float4*)plocs, tcls, npos, sums);
  k_focal<<<2048, 256, 0, stream>>>((const float4*)pscores, tcls, sums);
  k_final<<<1, 64, 0, stream>>>(npos, sums, out);
}

// Round 3
// 124.487 us; speedup vs baseline: 3.6089x; 1.0050x over previous
//
#include <hip/hip_runtime.h>
#include <cstdint>

static constexpr int B    = 16;
static constexpr int P    = 22536;
static constexpr int NOBJ = 32;
static constexpr int CHUNKS = (P + 255) / 256;   // 89
static constexpr int NBLK   = CHUNKS * B;        // 1424

// ---------------------------------------------------------------- K1: per-object argmax over priors
// One block per (image, object); block 0 also zeroes accumulators.
// Packed (iou_bits<<32)|~prior: u64 max => max iou, ties prefer smallest prior.
__global__ __launch_bounds__(256) void k_objbest(
    const float4* __restrict__ boxes, const float4* __restrict__ priors,
    unsigned long long* __restrict__ objbest,
    float* __restrict__ sums, int* __restrict__ npos,
    unsigned* __restrict__ counter) {
  if (blockIdx.x == 0 && threadIdx.x == 0) {
    sums[0] = 0.f; sums[1] = 0.f; *npos = 0; *counter = 0u;
  }
  const int b = blockIdx.x >> 5;          // / NOBJ
  const int o = blockIdx.x & (NOBJ - 1);
  float4 bx = boxes[b * NOBJ + o];
  float barea = (bx.z - bx.x) * (bx.w - bx.y);   // same op order as reference
  unsigned long long best = 0ull;
  for (int p = threadIdx.x; p < P; p += 256) {
    float4 pc = priors[p];
    float hx = pc.z * 0.5f, hy = pc.w * 0.5f;    // c/2. == c*0.5f exactly
    float px0 = pc.x - hx, py0 = pc.y - hy;
    float px1 = pc.x + hx, py1 = pc.y + hy;
    float parea = (px1 - px0) * (py1 - py0);
    float lx = fmaxf(bx.x, px0), ly = fmaxf(bx.y, py0);
    float rx = fminf(bx.z, px1), ry = fminf(bx.w, py1);
    float w = fmaxf(rx - lx, 0.f), h = fmaxf(ry - ly, 0.f);
    float inter = w * h;
    float iou = inter / (barea + parea - inter); // area_a + area_b order, like ref
    unsigned long long pk =
        ((unsigned long long)__float_as_uint(iou) << 32) |
        (unsigned long long)(unsigned)(~(unsigned)p);
    best = (pk > best) ? pk : best;
  }
  for (int off = 32; off > 0; off >>= 1) {
    unsigned long long other = __shfl_down(best, off, 64);
    best = (other > best) ? other : best;
  }
  __shared__ unsigned long long sb[4];
  int lane = threadIdx.x & 63, wid = threadIdx.x >> 6;
  if (lane == 0) sb[wid] = best;
  __syncthreads();
  if (threadIdx.x == 0) {
    unsigned long long r = sb[0];
    r = (sb[1] > r) ? sb[1] : r;
    r = (sb[2] > r) ? sb[2] : r;
    r = (sb[3] > r) ? sb[3] : r;
    objbest[blockIdx.x] = r;
  }
}

// ---------------------------------------------------------------- K2: everything else, fused
// Grid (CHUNKS, B), 256 threads. Per block: forced-list from objbest (ballot
// prefix = cumsum(valid)-1 quirk, j-ascending overwrite = last-writer-wins),
// per-prior IoU argmax, label + smooth-L1, coalesced focal over the block's
// 256x80 score slab, block reduce, last-block computes the final scalar.
__global__ __launch_bounds__(256) void k_main(
    const float4* __restrict__ plocs, const float4* __restrict__ scores,
    const float4* __restrict__ boxes, const int* __restrict__ labels,
    const float4* __restrict__ priors,
    const unsigned long long* __restrict__ objbest,
    float* __restrict__ sums, int* __restrict__ npos,
    unsigned* __restrict__ counter, float* __restrict__ out) {
  const int b    = blockIdx.y;
  const int base = blockIdx.x * 256;
  const int tid  = threadIdx.x;
  const int p    = base + tid;

  __shared__ float4 sbox[NOBJ];
  __shared__ float  sarea[NOBJ];
  __shared__ int    slab[NOBJ];
  __shared__ int    sfp[NOBJ];   // forced prior index (-1 if invalid)
  __shared__ int    sfc[NOBJ];   // filtered object index (cumsum(valid)-1)
  __shared__ int    scls[256];

  if (tid < NOBJ) {
    float4 bx = boxes[b * NOBJ + tid];
    sbox[tid]  = bx;
    sarea[tid] = (bx.z - bx.x) * (bx.w - bx.y);
    slab[tid]  = labels[b * NOBJ + tid];
    unsigned long long pk = objbest[b * NOBJ + tid];
    float iou  = __uint_as_float((unsigned)(pk >> 32));
    bool valid = iou > 0.f;
    unsigned long long m = __ballot(valid);       // lanes 32..63 inactive -> 0
    sfp[tid] = valid ? (int)(~(unsigned)(pk & 0xFFFFFFFFull)) : -1;
    sfc[tid] = (int)__popcll(m & ((1ull << tid) - 1ull));
  }
  __syncthreads();

  float ov = -1.f; int obj = 0; int lab = -1;
  float mySl1 = 0.f; int myPos = 0;
  if (p < P) {
    float4 pc = priors[p];
    float hx = pc.z * 0.5f, hy = pc.w * 0.5f;
    float px0 = pc.x - hx, py0 = pc.y - hy;
    float px1 = pc.x + hx, py1 = pc.y + hy;
    float parea = (px1 - px0) * (py1 - py0);
    #pragma unroll 8
    for (int o = 0; o < NOBJ; ++o) {
      float4 bx = sbox[o];
      float lx = fmaxf(bx.x, px0), ly = fmaxf(bx.y, py0);
      float rx = fminf(bx.z, px1), ry = fminf(bx.w, py1);
      float w = fmaxf(rx - lx, 0.f), h = fmaxf(ry - ly, 0.f);
      float inter = w * h;
      float iou = inter / (sarea[o] + parea - inter);
      if (iou > ov) { ov = iou; obj = o; }       // strict >: first max wins
    }
    #pragma unroll
    for (int j = 0; j < NOBJ; ++j) {             // ascending j: last writer wins
      if (sfp[j] == p) { ov = 1.0f; obj = sfc[j]; }
    }
    if (ov < 0.4f)      lab = 0;                 // fp32(0.5-0.1) == 0.4f
    else if (ov < 0.5f) lab = -1;
    else                lab = slab[obj];
    if (lab > 0) {
      myPos = 1;
      float4 bx = sbox[obj];                     // quirky filtered index, like ref
      float cx = (bx.x + bx.z) * 0.5f;
      float cy = (bx.y + bx.w) * 0.5f;
      float cw = bx.z - bx.x;
      float ch = bx.w - bx.y;
      float gx = (cx - pc.x) / (pc.z / 10.f);    // keep the /10. division
      float gy = (cy - pc.y) / (pc.w / 10.f);
      float gw = logf(cw / pc.z) * 5.f;
      float gh = logf(ch / pc.w) * 5.f;
      float4 pl = plocs[(size_t)b * P + p];
      float d, a;
      d = pl.x - gx; a = fabsf(d); mySl1 += (a < 1.f) ? 0.5f * d * d : a - 0.5f;
      d = pl.y - gy; a = fabsf(d); mySl1 += (a < 1.f) ? 0.5f * d * d : a - 0.5f;
      d = pl.z - gw; a = fabsf(d); mySl1 += (a < 1.f) ? 0.5f * d * d : a - 0.5f;
      d = pl.w - gh; a = fabsf(d); mySl1 += (a < 1.f) ? 0.5f * d * d : a - 0.5f;
    }
  }
  scls[tid] = lab;                               // -1 for p>=P: zero contribution
  __syncthreads();

  // focal: block-local coalesced pass over 256 priors x 20 float4
  float acc = 0.f;
  const float4* srow = scores + ((size_t)b * P + base) * 20;
  int lim = P - base; if (lim > 256) lim = 256; lim *= 20;
  for (int k = 0; k < 20; ++k) {
    int idx = tid + k * 256;                     // consecutive lanes -> consecutive float4
    if (idx < lim) {
      int pl_ = idx / 20;
      int t = scls[pl_];
      if (t >= 0) {
        float4 s = srow[idx];
        int kb = (idx - pl_ * 20) * 4 + 1;       // 1-indexed class of s.x
        float xs[4] = {s.x, s.y, s.z, s.w};
        #pragma unroll
        for (int j = 0; j < 4; ++j) {
          float x   = xs[j];
          float e   = __expf(-x);
          float r   = __builtin_amdgcn_rcpf(1.f + e);  // p = sigmoid(x)
          float lsp = -__logf(1.f + e);                // log sigmoid(x)
          bool  pos = (t == kb + j);
          float c   = pos ? 0.25f : 0.75f;
          float q   = pos ? e * r : r;                 // (1-p) : p
          float l   = pos ? lsp : lsp - x;             // logp : logn
          acc -= c * q * q * l;
        }
      }
    }
  }

  for (int off = 32; off > 0; off >>= 1) {
    acc   += __shfl_down(acc,   off, 64);
    mySl1 += __shfl_down(mySl1, off, 64);
    myPos += __shfl_down(myPos, off, 64);
  }
  __shared__ float svF[4], svS[4];
  __shared__ int   svP[4];
  int lane = tid & 63, wid = tid >> 6;
  if (lane == 0) { svF[wid] = acc; svS[wid] = mySl1; svP[wid] = myPos; }
  __syncthreads();
  if (tid == 0) {
    atomicAdd(&sums[1], svF[0] + svF[1] + svF[2] + svF[3]);
    atomicAdd(&sums[0], svS[0] + svS[1] + svS[2] + svS[3]);
    atomicAdd(npos,     svP[0] + svP[1] + svP[2] + svP[3]);
    __threadfence();
    unsigned done = atomicAdd(counter, 1u);
    if (done == NBLK - 1) {                      // last block finalizes
      float s1 = atomicAdd(&sums[1], 0.f);       // atomic reads: coherent point
      float s0 = atomicAdd(&sums[0], 0.f);
      int   n  = atomicAdd(npos, 0);
      float np = (float)(n >= 1 ? n : 1);
      out[0] = s1 / np + s0 / (np * 4.f);
    }
  }
}

// ---------------------------------------------------------------- launch
extern "C" void kernel_launch(void* const* d_in, const int* in_sizes, int n_in,
                              void* d_out, int out_size, void* d_ws, size_t ws_size,
                              hipStream_t stream) {
  const float* plocs   = (const float*)d_in[0];   // [B,P,4]
  const float* pscores = (const float*)d_in[1];   // [B,P,80]
  const float* boxes   = (const float*)d_in[2];   // [B,32,4]
  const int*   labels  = (const int*)d_in[3];     // [B,32]
  const float* priors  = (const float*)d_in[4];   // [P,4]
  float* out = (float*)d_out;

  char* w = (char*)d_ws;
  unsigned long long* objbest = (unsigned long long*)w;        // B*NOBJ u64 = 4 KB
  float*    sums    = (float*)(w + 8ull * B * NOBJ);           // 2 floats
  int*      npos    = (int*)(w + 8ull * B * NOBJ + 8);
  unsigned* counter = (unsigned*)(w + 8ull * B * NOBJ + 12);

  k_objbest<<<B * NOBJ, 256, 0, stream>>>(
      (const float4*)boxes, (const float4*)priors, objbest, sums, npos, counter);
  dim3 g(CHUNKS, B);
  k_main<<<g, 256, 0, stream>>>(
      (const float4*)plocs, (const float4*)pscores, (const float4*)boxes,
      labels, (const float4*)priors, objbest, sums, npos, counter, out);
}

// Round 4
// 112.971 us; speedup vs baseline: 3.9768x; 1.1019x over previous
//
#include <hip/hip_runtime.h>
#include <cstdint>

static constexpr int B    = 16;
static constexpr int P    = 22536;
static constexpr int NOBJ = 32;
static constexpr int CHUNKS = (P + 255) / 256;   // 89
static constexpr int BP   = B * P;

// ---------------------------------------------------------------- K1: per-object argmax over priors
// One block per (image, object); block 0 also zeroes accumulators.
// Packed (iou_bits<<32)|~prior: u64 max => max iou, ties prefer smallest prior.
__global__ __launch_bounds__(256) void k_objbest(
    const float4* __restrict__ boxes, const float4* __restrict__ priors,
    unsigned long long* __restrict__ objbest,
    float* __restrict__ sums, int* __restrict__ npos) {
  if (blockIdx.x == 0 && threadIdx.x == 0) {
    sums[0] = 0.f; sums[1] = 0.f; *npos = 0;
  }
  const int b = blockIdx.x >> 5;          // / NOBJ
  const int o = blockIdx.x & (NOBJ - 1);
  float4 bx = boxes[b * NOBJ + o];
  float barea = (bx.z - bx.x) * (bx.w - bx.y);   // same op order as reference
  unsigned long long best = 0ull;
  for (int p = threadIdx.x; p < P; p += 256) {
    float4 pc = priors[p];
    float hx = pc.z * 0.5f, hy = pc.w * 0.5f;    // c/2. == c*0.5f exactly
    float px0 = pc.x - hx, py0 = pc.y - hy;
    float px1 = pc.x + hx, py1 = pc.y + hy;
    float parea = (px1 - px0) * (py1 - py0);
    float lx = fmaxf(bx.x, px0), ly = fmaxf(bx.y, py0);
    float rx = fminf(bx.z, px1), ry = fminf(bx.w, py1);
    float w = fmaxf(rx - lx, 0.f), h = fmaxf(ry - ly, 0.f);
    float inter = w * h;
    float iou = inter / (barea + parea - inter); // IEEE div, matches reference bits
    unsigned long long pk =
        ((unsigned long long)__float_as_uint(iou) << 32) |
        (unsigned long long)(unsigned)(~(unsigned)p);
    best = (pk > best) ? pk : best;
  }
  for (int off = 32; off > 0; off >>= 1) {
    unsigned long long other = __shfl_down(best, off, 64);
    best = (other > best) ? other : best;
  }
  __shared__ unsigned long long sb[4];
  int lane = threadIdx.x & 63, wid = threadIdx.x >> 6;
  if (lane == 0) sb[wid] = best;
  __syncthreads();
  if (threadIdx.x == 0) {
    unsigned long long r = sb[0];
    r = (sb[1] > r) ? sb[1] : r;
    r = (sb[2] > r) ? sb[2] : r;
    r = (sb[3] > r) ? sb[3] : r;
    objbest[blockIdx.x] = r;
  }
}

// ---------------------------------------------------------------- K2: match + force + classloc
// Grid (CHUNKS, B). Writes tclass[] to global; accumulates smooth-L1 + npos.
__global__ __launch_bounds__(256) void k_prep(
    const float4* __restrict__ plocs, const float4* __restrict__ boxes,
    const int* __restrict__ labels, const float4* __restrict__ priors,
    const unsigned long long* __restrict__ objbest,
    int* __restrict__ tclass, float* __restrict__ sums, int* __restrict__ npos) {
  const int b    = blockIdx.y;
  const int base = blockIdx.x * 256;
  const int tid  = threadIdx.x;
  const int p    = base + tid;

  __shared__ float4 sbox[NOBJ];
  __shared__ float  sarea[NOBJ];
  __shared__ int    slab[NOBJ];
  __shared__ int    sfp[NOBJ];   // forced prior index (-1 if invalid)
  __shared__ int    sfc[NOBJ];   // filtered object index (cumsum(valid)-1)

  if (tid < NOBJ) {
    float4 bx = boxes[b * NOBJ + tid];
    sbox[tid]  = bx;
    sarea[tid] = (bx.z - bx.x) * (bx.w - bx.y);
    slab[tid]  = labels[b * NOBJ + tid];
    unsigned long long pk = objbest[b * NOBJ + tid];
    float iou  = __uint_as_float((unsigned)(pk >> 32));
    bool valid = iou > 0.f;
    unsigned long long m = __ballot(valid);       // lanes 32..63 inactive -> 0
    sfp[tid] = valid ? (int)(~(unsigned)(pk & 0xFFFFFFFFull)) : -1;
    sfc[tid] = (int)__popcll(m & ((1ull << tid) - 1ull));
  }
  __syncthreads();

  float mySl1 = 0.f; int myPos = 0; int lab = -1;
  if (p < P) {
    float4 pc = priors[p];
    float hx = pc.z * 0.5f, hy = pc.w * 0.5f;
    float px0 = pc.x - hx, py0 = pc.y - hy;
    float px1 = pc.x + hx, py1 = pc.y + hy;
    float parea = (px1 - px0) * (py1 - py0);
    float ov = -1.f; int obj = 0;
    #pragma unroll 8
    for (int o = 0; o < NOBJ; ++o) {
      float4 bx = sbox[o];
      float lx = fmaxf(bx.x, px0), ly = fmaxf(bx.y, py0);
      float rx = fminf(bx.z, px1), ry = fminf(bx.w, py1);
      float w = fmaxf(rx - lx, 0.f), h = fmaxf(ry - ly, 0.f);
      float inter = w * h;
      float iou = inter / (sarea[o] + parea - inter);
      if (iou > ov) { ov = iou; obj = o; }       // strict >: first max wins
    }
    #pragma unroll
    for (int j = 0; j < NOBJ; ++j) {             // ascending j: last writer wins
      if (sfp[j] == p) { ov = 1.0f; obj = sfc[j]; }
    }
    if (ov < 0.4f)      lab = 0;                 // fp32(0.5-0.1) == 0.4f
    else if (ov < 0.5f) lab = -1;
    else                lab = slab[obj];
    tclass[b * P + p] = lab;
    if (lab > 0) {
      myPos = 1;
      float4 bx = sbox[obj];                     // quirky filtered index, like ref
      float cx = (bx.x + bx.z) * 0.5f;
      float cy = (bx.y + bx.w) * 0.5f;
      float cw = bx.z - bx.x;
      float ch = bx.w - bx.y;
      float gx = (cx - pc.x) / (pc.z / 10.f);    // keep the /10. division
      float gy = (cy - pc.y) / (pc.w / 10.f);
      float gw = logf(cw / pc.z) * 5.f;
      float gh = logf(ch / pc.w) * 5.f;
      float4 pl = plocs[(size_t)b * P + p];
      float d, a;
      d = pl.x - gx; a = fabsf(d); mySl1 += (a < 1.f) ? 0.5f * d * d : a - 0.5f;
      d = pl.y - gy; a = fabsf(d); mySl1 += (a < 1.f) ? 0.5f * d * d : a - 0.5f;
      d = pl.z - gw; a = fabsf(d); mySl1 += (a < 1.f) ? 0.5f * d * d : a - 0.5f;
      d = pl.w - gh; a = fabsf(d); mySl1 += (a < 1.f) ? 0.5f * d * d : a - 0.5f;
    }
  }
  for (int off = 32; off > 0; off >>= 1) {
    mySl1 += __shfl_down(mySl1, off, 64);
    myPos += __shfl_down(myPos, off, 64);
  }
  __shared__ float sv[4];
  __shared__ int   sc[4];
  int lane = tid & 63, wid = tid >> 6;
  if (lane == 0) { sv[wid] = mySl1; sc[wid] = myPos; }
  __syncthreads();
  if (tid == 0) {
    atomicAdd(&sums[0], sv[0] + sv[1] + sv[2] + sv[3]);
    atomicAdd(npos,     sc[0] + sc[1] + sc[2] + sc[3]);
  }
}

// ---------------------------------------------------------------- K3: focal, branch-free main loop
// Each thread: 4 consecutive float4 (16 elems, one prior row segment -> one t).
// Neg path for all (w=0 masks ignore); rare positive-class correction branch.
// loss_neg = 0.75*p^2*(x+log u); loss_pos = 0.25*(1-p)^2*log u; u=1+e^-x, p=1/u.
__global__ __launch_bounds__(256) void k_focal(
    const float4* __restrict__ scores, const int* __restrict__ tclass,
    float* __restrict__ sums) {
  constexpr int Q = 20;                    // float4 per prior
  constexpr int total4 = BP * Q;           // 7,211,520 (multiple of 4)
  float acc = 0.f;
  int i0 = (blockIdx.x * 256 + threadIdx.x) * 4;
  const int step = gridDim.x * 256 * 4;
  for (; i0 < total4; i0 += step) {
    float4 s0 = scores[i0 + 0];
    float4 s1 = scores[i0 + 1];
    float4 s2 = scores[i0 + 2];
    float4 s3 = scores[i0 + 3];
    int pl = i0 / Q;                       // i0%4==0 && 20%4==0 -> same prior for all 4
    int t  = tclass[pl];
    int kb = (i0 - pl * Q) * 4 + 1;        // 1-indexed class of s0.x
    float w = (t >= 0) ? 0.75f : 0.f;      // mask ignore(-1) without a branch
    float xs[16] = {s0.x, s0.y, s0.z, s0.w, s1.x, s1.y, s1.z, s1.w,
                    s2.x, s2.y, s2.z, s2.w, s3.x, s3.y, s3.z, s3.w};
    float accl = 0.f;
    #pragma unroll
    for (int j = 0; j < 16; ++j) {
      float x  = xs[j];
      float e  = __expf(-x);
      float u  = 1.f + e;
      float r  = __builtin_amdgcn_rcpf(u);
      float lu = __logf(u);
      accl += (x + lu) * (r * r);
    }
    acc += w * accl;
    unsigned d = (unsigned)(t - kb);       // t==kb+d with d<16 iff positive here
    if (d < 16u) {
      float4 sv = (d < 8u) ? ((d < 4u) ? s0 : s1) : ((d < 12u) ? s2 : s3);
      unsigned dj = d & 3u;
      float x  = (dj < 2u) ? ((dj == 0u) ? sv.x : sv.y)
                           : ((dj == 2u) ? sv.z : sv.w);
      float e  = __expf(-x);
      float u  = 1.f + e;
      float r  = __builtin_amdgcn_rcpf(u);
      float lu = __logf(u);
      float omp = e * r;                   // 1-p
      acc += 0.25f * omp * omp * lu - 0.75f * (x + lu) * (r * r);
    }
  }
  for (int off = 32; off > 0; off >>= 1) acc += __shfl_down(acc, off, 64);
  __shared__ float sv[4];
  int lane = threadIdx.x & 63, wid = threadIdx.x >> 6;
  if (lane == 0) sv[wid] = acc;
  __syncthreads();
  if (threadIdx.x == 0) atomicAdd(&sums[1], sv[0] + sv[1] + sv[2] + sv[3]);
}

// ---------------------------------------------------------------- K4: finalize
__global__ void k_final(const int* __restrict__ npos,
                        const float* __restrict__ sums, float* __restrict__ out) {
  if (threadIdx.x == 0 && blockIdx.x == 0) {
    int n = *npos;
    float np = (float)(n >= 1 ? n : 1);
    out[0] = sums[1] / np + sums[0] / (np * 4.f);
  }
}

// ---------------------------------------------------------------- launch
extern "C" void kernel_launch(void* const* d_in, const int* in_sizes, int n_in,
                              void* d_out, int out_size, void* d_ws, size_t ws_size,
                              hipStream_t stream) {
  const float* plocs   = (const float*)d_in[0];   // [B,P,4]
  const float* pscores = (const float*)d_in[1];   // [B,P,80]
  const float* boxes   = (const float*)d_in[2];   // [B,32,4]
  const int*   labels  = (const int*)d_in[3];     // [B,32]
  const float* priors  = (const float*)d_in[4];   // [P,4]
  float* out = (float*)d_out;

  char* w = (char*)d_ws;
  unsigned long long* objbest = (unsigned long long*)w;  // B*NOBJ u64 = 4 KB
  float* sums = (float*)(w + 8ull * B * NOBJ);           // 2 floats
  int*   npos = (int*)(w + 8ull * B * NOBJ + 8);
  int*   tcls = (int*)(w + 8192);                        // BP ints

  k_objbest<<<B * NOBJ, 256, 0, stream>>>(
      (const float4*)boxes, (const float4*)priors, objbest, sums, npos);
  dim3 g(CHUNKS, B);
  k_prep<<<g, 256, 0, stream>>>(
      (const float4*)plocs, (const float4*)boxes, labels, (const float4*)priors,
      objbest, tcls, sums, npos);
  k_focal<<<2048, 256, 0, stream>>>((const float4*)pscores, tcls, sums);
  k_final<<<1, 64, 0, stream>>>(npos, sums, out);
}

// Round 5
// 79.610 us; speedup vs baseline: 5.6432x; 1.4191x over previous
//
#include <hip/hip_runtime.h>
#include <cstdint>

static constexpr int B    = 16;
static constexpr int P    = 22536;
static constexpr int NOBJ = 32;
static constexpr int CHUNKS = (P + 255) / 256;   // 89
static constexpr int PREPB  = CHUNKS * B;        // 1424
static constexpr int BP   = B * P;
static constexpr int Q4   = 20;                  // float4 per prior
static constexpr int TOTAL4 = BP * Q4;           // 7,211,520
static constexpr int FB   = 2048;                // focal blocks

// ---------------------------------------------------------------- K1: per-object argmax over priors
// One block per (image, object). Packed (iou_bits<<32)|~prior: u64 max =>
// max iou, ties prefer smallest prior (first-occurrence, like jnp.argmax).
__global__ __launch_bounds__(256) void k_objbest(
    const float4* __restrict__ boxes, const float4* __restrict__ priors,
    unsigned long long* __restrict__ objbest) {
  const int b = blockIdx.x >> 5;          // / NOBJ
  const int o = blockIdx.x & (NOBJ - 1);
  float4 bx = boxes[b * NOBJ + o];
  float barea = (bx.z - bx.x) * (bx.w - bx.y);   // same op order as reference
  unsigned long long best = 0ull;
  for (int p = threadIdx.x; p < P; p += 256) {
    float4 pc = priors[p];
    float hx = pc.z * 0.5f, hy = pc.w * 0.5f;    // c/2. == c*0.5f exactly
    float px0 = pc.x - hx, py0 = pc.y - hy;
    float px1 = pc.x + hx, py1 = pc.y + hy;
    float parea = (px1 - px0) * (py1 - py0);
    float lx = fmaxf(bx.x, px0), ly = fmaxf(bx.y, py0);
    float rx = fminf(bx.z, px1), ry = fminf(bx.w, py1);
    float w = fmaxf(rx - lx, 0.f), h = fmaxf(ry - ly, 0.f);
    float inter = w * h;
    float iou = inter / (barea + parea - inter); // IEEE div, matches reference bits
    unsigned long long pk =
        ((unsigned long long)__float_as_uint(iou) << 32) |
        (unsigned long long)(unsigned)(~(unsigned)p);
    best = (pk > best) ? pk : best;
  }
  for (int off = 32; off > 0; off >>= 1) {
    unsigned long long other = __shfl_down(best, off, 64);
    best = (other > best) ? other : best;
  }
  __shared__ unsigned long long sb[4];
  int lane = threadIdx.x & 63, wid = threadIdx.x >> 6;
  if (lane == 0) sb[wid] = best;
  __syncthreads();
  if (threadIdx.x == 0) {
    unsigned long long r = sb[0];
    r = (sb[1] > r) ? sb[1] : r;
    r = (sb[2] > r) ? sb[2] : r;
    r = (sb[3] > r) ? sb[3] : r;
    objbest[blockIdx.x] = r;
  }
}

// ---------------------------------------------------------------- K2: match + force + classloc
// Grid (CHUNKS, B). Writes tclass[]; per-block partials (no atomics).
__global__ __launch_bounds__(256) void k_prep(
    const float4* __restrict__ plocs, const float4* __restrict__ boxes,
    const int* __restrict__ labels, const float4* __restrict__ priors,
    const unsigned long long* __restrict__ objbest,
    int* __restrict__ tclass, float* __restrict__ partS, int* __restrict__ partN) {
  const int b    = blockIdx.y;
  const int base = blockIdx.x * 256;
  const int tid  = threadIdx.x;
  const int p    = base + tid;

  __shared__ float4 sbox[NOBJ];
  __shared__ float  sarea[NOBJ];
  __shared__ int    slab[NOBJ];
  __shared__ int    sfp[NOBJ];   // forced prior index (-1 if invalid)
  __shared__ int    sfc[NOBJ];   // filtered object index (cumsum(valid)-1)

  if (tid < NOBJ) {
    float4 bx = boxes[b * NOBJ + tid];
    sbox[tid]  = bx;
    sarea[tid] = (bx.z - bx.x) * (bx.w - bx.y);
    slab[tid]  = labels[b * NOBJ + tid];
    unsigned long long pk = objbest[b * NOBJ + tid];
    float iou  = __uint_as_float((unsigned)(pk >> 32));
    bool valid = iou > 0.f;
    unsigned long long m = __ballot(valid);       // lanes 32..63 inactive -> 0
    sfp[tid] = valid ? (int)(~(unsigned)(pk & 0xFFFFFFFFull)) : -1;
    sfc[tid] = (int)__popcll(m & ((1ull << tid) - 1ull));
  }
  __syncthreads();

  float mySl1 = 0.f; int myPos = 0; int lab = -1;
  if (p < P) {
    float4 pc = priors[p];
    float hx = pc.z * 0.5f, hy = pc.w * 0.5f;
    float px0 = pc.x - hx, py0 = pc.y - hy;
    float px1 = pc.x + hx, py1 = pc.y + hy;
    float parea = (px1 - px0) * (py1 - py0);
    float ov = -1.f; int obj = 0;
    #pragma unroll 8
    for (int o = 0; o < NOBJ; ++o) {
      float4 bx = sbox[o];
      float lx = fmaxf(bx.x, px0), ly = fmaxf(bx.y, py0);
      float rx = fminf(bx.z, px1), ry = fminf(bx.w, py1);
      float w = fmaxf(rx - lx, 0.f), h = fmaxf(ry - ly, 0.f);
      float inter = w * h;
      float iou = inter / (sarea[o] + parea - inter);
      if (iou > ov) { ov = iou; obj = o; }       // strict >: first max wins
    }
    #pragma unroll
    for (int j = 0; j < NOBJ; ++j) {             // ascending j: last writer wins
      if (sfp[j] == p) { ov = 1.0f; obj = sfc[j]; }
    }
    if (ov < 0.4f)      lab = 0;                 // fp32(0.5-0.1) == 0.4f
    else if (ov < 0.5f) lab = -1;
    else                lab = slab[obj];
    tclass[b * P + p] = lab;
    if (lab > 0) {
      myPos = 1;
      float4 bx = sbox[obj];                     // quirky filtered index, like ref
      float cx = (bx.x + bx.z) * 0.5f;
      float cy = (bx.y + bx.w) * 0.5f;
      float cw = bx.z - bx.x;
      float ch = bx.w - bx.y;
      float gx = (cx - pc.x) / (pc.z / 10.f);    // keep the /10. division
      float gy = (cy - pc.y) / (pc.w / 10.f);
      float gw = logf(cw / pc.z) * 5.f;
      float gh = logf(ch / pc.w) * 5.f;
      float4 pl = plocs[(size_t)b * P + p];
      float d, a;
      d = pl.x - gx; a = fabsf(d); mySl1 += (a < 1.f) ? 0.5f * d * d : a - 0.5f;
      d = pl.y - gy; a = fabsf(d); mySl1 += (a < 1.f) ? 0.5f * d * d : a - 0.5f;
      d = pl.z - gw; a = fabsf(d); mySl1 += (a < 1.f) ? 0.5f * d * d : a - 0.5f;
      d = pl.w - gh; a = fabsf(d); mySl1 += (a < 1.f) ? 0.5f * d * d : a - 0.5f;
    }
  }
  for (int off = 32; off > 0; off >>= 1) {
    mySl1 += __shfl_down(mySl1, off, 64);
    myPos += __shfl_down(myPos, off, 64);
  }
  __shared__ float sv[4];
  __shared__ int   sc[4];
  int lane = tid & 63, wid = tid >> 6;
  if (lane == 0) { sv[wid] = mySl1; sc[wid] = myPos; }
  __syncthreads();
  if (tid == 0) {
    partS[b * CHUNKS + blockIdx.x] = sv[0] + sv[1] + sv[2] + sv[3];
    partN[b * CHUNKS + blockIdx.x] = sc[0] + sc[1] + sc[2] + sc[3];
  }
}

// ---------------------------------------------------------------- K3: focal
// Lane-consecutive float4 per load instruction; 8 independent loads in flight.
// Neg path for all (w=0 masks ignore); rare positive-class correction branch.
// loss_neg = 0.75*p^2*(x+log u); loss_pos = 0.25*(1-p)^2*log u; u=1+e^-x, p=1/u.
__global__ __launch_bounds__(256) void k_focal(
    const float4* __restrict__ scores, const int* __restrict__ tclass,
    float* __restrict__ partF) {
  const int tid = threadIdx.x;
  float acc = 0.f;
  for (int base = blockIdx.x * 2048; base < TOTAL4; base += FB * 2048) {
    if (base + 2048 <= TOTAL4) {
      float4 s[8];
      const int idx0 = base + tid;
      #pragma unroll
      for (int k = 0; k < 8; ++k) s[k] = scores[idx0 + k * 256];  // coalesced
      #pragma unroll
      for (int k = 0; k < 8; ++k) {
        int idx = idx0 + k * 256;
        int pl  = idx / Q4;
        int t   = tclass[pl];
        int kb  = (idx - pl * Q4) * 4 + 1;       // 1-indexed class of s[k].x
        float w = (t >= 0) ? 0.75f : 0.f;        // mask ignore(-1), no branch
        float xs[4] = {s[k].x, s[k].y, s[k].z, s[k].w};
        float accl = 0.f;
        #pragma unroll
        for (int j = 0; j < 4; ++j) {
          float x  = xs[j];
          float e  = __expf(-x);
          float u  = 1.f + e;
          float r  = __builtin_amdgcn_rcpf(u);
          float lu = __logf(u);
          accl += (x + lu) * (r * r);
        }
        acc += w * accl;
        unsigned d = (unsigned)(t - kb);         // t==kb+d, d<4 iff positive here
        if (d < 4u) {
          float x  = (d < 2u) ? ((d == 0u) ? s[k].x : s[k].y)
                              : ((d == 2u) ? s[k].z : s[k].w);
          float e  = __expf(-x);
          float u  = 1.f + e;
          float r  = __builtin_amdgcn_rcpf(u);
          float lu = __logf(u);
          float omp = e * r;                     // 1-p
          acc += 0.25f * omp * omp * lu - 0.75f * (x + lu) * (r * r);
        }
      }
    } else {                                     // tail block (rare)
      for (int k = 0; k < 8; ++k) {
        int idx = base + tid + k * 256;
        if (idx < TOTAL4) {
          float4 sv = scores[idx];
          int pl = idx / Q4;
          int t  = tclass[pl];
          int kb = (idx - pl * Q4) * 4 + 1;
          float w = (t >= 0) ? 0.75f : 0.f;
          float xs[4] = {sv.x, sv.y, sv.z, sv.w};
          float accl = 0.f;
          #pragma unroll
          for (int j = 0; j < 4; ++j) {
            float x  = xs[j];
            float e  = __expf(-x);
            float u  = 1.f + e;
            float r  = __builtin_amdgcn_rcpf(u);
            float lu = __logf(u);
            accl += (x + lu) * (r * r);
          }
          acc += w * accl;
          unsigned d = (unsigned)(t - kb);
          if (d < 4u) {
            float x  = (d < 2u) ? ((d == 0u) ? sv.x : sv.y)
                                : ((d == 2u) ? sv.z : sv.w);
            float e  = __expf(-x);
            float u  = 1.f + e;
            float r  = __builtin_amdgcn_rcpf(u);
            float lu = __logf(u);
            float omp = e * r;
            acc += 0.25f * omp * omp * lu - 0.75f * (x + lu) * (r * r);
          }
        }
      }
    }
  }
  for (int off = 32; off > 0; off >>= 1) acc += __shfl_down(acc, off, 64);
  __shared__ float sv[4];
  int lane = tid & 63, wid = tid >> 6;
  if (lane == 0) sv[wid] = acc;
  __syncthreads();
  if (tid == 0) partF[blockIdx.x] = sv[0] + sv[1] + sv[2] + sv[3];
}

// ---------------------------------------------------------------- K4: final reduce
__global__ __launch_bounds__(256) void k_final(
    const float* __restrict__ partF, const float* __restrict__ partS,
    const int* __restrict__ partN, float* __restrict__ out) {
  const int tid = threadIdx.x;
  float sF = 0.f, sS = 0.f; int sN = 0;
  for (int i = tid; i < FB; i += 256) sF += partF[i];
  for (int i = tid; i < PREPB; i += 256) { sS += partS[i]; sN += partN[i]; }
  for (int off = 32; off > 0; off >>= 1) {
    sF += __shfl_down(sF, off, 64);
    sS += __shfl_down(sS, off, 64);
    sN += __shfl_down(sN, off, 64);
  }
  __shared__ float vF[4], vS[4];
  __shared__ int   vN[4];
  int lane = tid & 63, wid = tid >> 6;
  if (lane == 0) { vF[wid] = sF; vS[wid] = sS; vN[wid] = sN; }
  __syncthreads();
  if (tid == 0) {
    float f = vF[0] + vF[1] + vF[2] + vF[3];
    float s = vS[0] + vS[1] + vS[2] + vS[3];
    int   n = vN[0] + vN[1] + vN[2] + vN[3];
    float np = (float)(n >= 1 ? n : 1);
    out[0] = f / np + s / (np * 4.f);
  }
}

// ---------------------------------------------------------------- launch
extern "C" void kernel_launch(void* const* d_in, const int* in_sizes, int n_in,
                              void* d_out, int out_size, void* d_ws, size_t ws_size,
                              hipStream_t stream) {
  const float* plocs   = (const float*)d_in[0];   // [B,P,4]
  const float* pscores = (const float*)d_in[1];   // [B,P,80]
  const float* boxes   = (const float*)d_in[2];   // [B,32,4]
  const int*   labels  = (const int*)d_in[3];     // [B,32]
  const float* priors  = (const float*)d_in[4];   // [P,4]
  float* out = (float*)d_out;

  char* w = (char*)d_ws;
  unsigned long long* objbest = (unsigned long long*)w;  // 512 u64   @0
  float* partF = (float*)(w + 4096);                     // FB floats @4096
  float* partS = (float*)(w + 4096 + 4 * FB);            // PREPB floats
  int*   partN = (int*)(w + 4096 + 4 * FB + 4 * PREPB);  // PREPB ints
  int*   tcls  = (int*)(w + 65536);                      // BP ints

  k_objbest<<<B * NOBJ, 256, 0, stream>>>(
      (const float4*)boxes, (const float4*)priors, objbest);
  dim3 g(CHUNKS, B);
  k_prep<<<g, 256, 0, stream>>>(
      (const float4*)plocs, (const float4*)boxes, labels, (const float4*)priors,
      objbest, tcls, partS, partN);
  k_focal<<<FB, 256, 0, stream>>>((const float4*)pscores, tcls, partF);
  k_final<<<1, 256, 0, stream>>>(partF, partS, partN, out);
}